// Round 6
// baseline (927.235 us; speedup 1.0000x reference)
//
#include <hip/hip_runtime.h>
#include <stdint.h>

#define BATCH 64
#define NQ 300
#define NCH 84            // 4 + 80
#define KTOP 150
#define NTOT (NQ * NCH)   // 25200
#define KDIM 1200
#define NCHUNK 4
#define KCH 300           // K per chunk (4 chunks)
#define HW 640
#define PF 6              // W prefetch depth (KCH % PF == 0)

#define MARGIN_ARGMAX 1e-4f   // ~45x max statistical fp32 accum error (2.2e-6)
#define PAIR_BASE     2e-5f   // rank-tightness radius (9x max fp32 error)
#define PAIR_INFLATE  1.2e-4f // extra radius near argmax-tight queries

// ws layout (bytes), fp32 pipeline + fp64 rescue:
//   At  : [0, 614400)            1200*64 double   (for fp64 rescue)
//   Af  : [614400, 921600)       1200*64 float    (GEMM A operand)
//   Yf  : [921600, 26726400)     4 * 64*25200 float (K-chunk partials)
//   sc  : [26726400, 26880000)   64*300 double  (final ranking scores)
//   sc32: [26880000, 26956800)   64*300 float   (fp32 scores for pair scan)
//   cid : [26956800, 27033600)   64*300 int
//   flg : [27033600, 27110400)   64*300 int  (bit0: argmax-tight, bit1: rank-tight)
#define WS_AF   614400
#define WS_YF   921600
#define WS_SC   26726400
#define WS_SC32 26880000
#define WS_CID  26956800
#define WS_FLG  27033600

// ---------------- Kernel 1: 32x32 average pool (exact int sum) --------------
// x: (64,3,640,640) int32 -> At (fp64) and Af (fp32), both [k*64+b], where
// flat k = c_new*400 + ph*20 + pw, c_new = 2 - c_in (BGR flip).
// (float)s exact (s <= 261120 < 2^24); single rounding on the scale.
__global__ __launch_bounds__(256) void pool_kernel(const int* __restrict__ x,
                                                   double* __restrict__ At,
                                                   float* __restrict__ Af) {
  int wave = threadIdx.x >> 6;
  int lane = threadIdx.x & 63;
  int cell = blockIdx.x * 4 + wave;            // 0 .. 76799
  int b   = cell / 1200;
  int rem = cell - b * 1200;
  int cin = rem / 400;
  int pp  = rem - cin * 400;                   // ph*20 + pw
  int ph = pp / 20, pw = pp - ph * 20;
  const int* base = x + (((b * 3 + cin) * HW) + ph * 32) * HW + pw * 32;
  int r  = lane >> 1;                          // 0..31 (row in block)
  int c0 = (lane & 1) * 16;                    // 0 or 16 (col in block)
  const int4* p = (const int4*)(base + r * HW + c0);
  int4 v0 = p[0], v1 = p[1], v2 = p[2], v3 = p[3];
  int s = v0.x + v0.y + v0.z + v0.w + v1.x + v1.y + v1.z + v1.w
        + v2.x + v2.y + v2.z + v2.w + v3.x + v3.y + v3.z + v3.w;
  #pragma unroll
  for (int off = 32; off > 0; off >>= 1) s += __shfl_down(s, off);
  if (lane == 0) {
    int kout = (2 - cin) * 400 + pp;
    At[kout * 64 + b] = (double)s * (1.0 / 261120.0);   // / (255*1024)
    Af[kout * 64 + b] = (float)s * (1.0f / 261120.0f);
  }
}

// ---------------- Kernel 2: fp32 GEMM, W-read-once, 2 cols/lane -------------
// Af: (1200,64) float  W: (1200,25200) float  Yf: (4, 64, 25200) float
// blockIdx.y = K chunk. 512-thread block = 8 waves x 8 rows = all 64 rows
// (W read exactly once); each lane owns 2 adjacent output columns (float2 W
// load, float2 Y store), A as two float4 per k. fp32 FMA = 2 cyc -> ~25 us
// issue floor (fp64 was the invariant 49 us floor across rounds 3-5).
// Decisions are guarded downstream by fp64 rescue (see argmax/pairscan).
__global__ __launch_bounds__(512) void gemm_kernel(const float* __restrict__ Af,
                                                   const float* __restrict__ W,
                                                   float* __restrict__ Yf) {
  int wave  = threadIdx.x >> 6;
  int lane  = threadIdx.x & 63;
  int chunk = blockIdx.y;
  int row0  = __builtin_amdgcn_readfirstlane((int)(wave * 8));
  int n  = blockIdx.x * 128 + 2 * lane;        // first of this lane's 2 cols
  int nl = n < NTOT - 1 ? n : NTOT - 2;        // clamp (even, no divergent load)
  const float4* Ap = (const float4*)(Af + (size_t)chunk * KCH * 64 + row0);
  const float*  Wp = W + (size_t)chunk * KCH * NTOT + nl;
  float acc0[8], acc1[8];
  #pragma unroll
  for (int i = 0; i < 8; ++i) { acc0[i] = 0.0f; acc1[i] = 0.0f; }
  float2 w[PF];
  #pragma unroll
  for (int u = 0; u < PF; ++u) w[u] = *(const float2*)(Wp + (size_t)u * NTOT);
  #pragma unroll 1
  for (int k0 = 0; k0 < KCH; k0 += PF) {
    int kn = (k0 + PF == KCH) ? 0 : k0 + PF;   // last prefetch wraps (unused)
    float2 wn[PF];
    #pragma unroll
    for (int u = 0; u < PF; ++u) wn[u] = *(const float2*)(Wp + (size_t)(kn + u) * NTOT);
    #pragma unroll
    for (int u = 0; u < PF; ++u) {
      float w0 = w[u].x, w1 = w[u].y;
      float4 a0 = Ap[(k0 + u) * 16 + 0];       // rows row0+0..3 at k=k0+u
      float4 a1 = Ap[(k0 + u) * 16 + 1];       // rows row0+4..7
      acc0[0] = fmaf(a0.x, w0, acc0[0]);  acc1[0] = fmaf(a0.x, w1, acc1[0]);
      acc0[1] = fmaf(a0.y, w0, acc0[1]);  acc1[1] = fmaf(a0.y, w1, acc1[1]);
      acc0[2] = fmaf(a0.z, w0, acc0[2]);  acc1[2] = fmaf(a0.z, w1, acc1[2]);
      acc0[3] = fmaf(a0.w, w0, acc0[3]);  acc1[3] = fmaf(a0.w, w1, acc1[3]);
      acc0[4] = fmaf(a1.x, w0, acc0[4]);  acc1[4] = fmaf(a1.x, w1, acc1[4]);
      acc0[5] = fmaf(a1.y, w0, acc0[5]);  acc1[5] = fmaf(a1.y, w1, acc1[5]);
      acc0[6] = fmaf(a1.z, w0, acc0[6]);  acc1[6] = fmaf(a1.z, w1, acc1[6]);
      acc0[7] = fmaf(a1.w, w0, acc0[7]);  acc1[7] = fmaf(a1.w, w1, acc1[7]);
    }
    #pragma unroll
    for (int u = 0; u < PF; ++u) w[u] = wn[u];
  }
  if (n < NTOT) {                              // n even -> n+1 also in range
    float* Yp = Yf + ((size_t)chunk * BATCH + row0) * NTOT + n;
    #pragma unroll
    for (int i = 0; i < 8; ++i) {
      float2 o; o.x = acc0[i]; o.y = acc1[i];
      *(float2*)(Yp + (size_t)i * NTOT) = o;
    }
  }
}

// ---------------- Kernel 3a: fp32 argmax + margin flag ----------------------
// One wave per (b,q). Fixed-order 4-partial sums; tracks best AND second-best.
// flags bit0 set when margin < MARGIN_ARGMAX (fp64 rescue needed).
__global__ __launch_bounds__(256) void argmax_kernel(const float* __restrict__ Yf,
                                                     double* __restrict__ sc,
                                                     float* __restrict__ sc32,
                                                     int* __restrict__ cid,
                                                     int* __restrict__ flg) {
  int wave = threadIdx.x >> 6;
  int lane = threadIdx.x & 63;
  int task = blockIdx.x * 4 + wave;            // 0 .. 19199
  int b = task / NQ;
  int q = task - b * NQ;
  const float* y = Yf + (size_t)b * NTOT + q * NCH;
  const size_t P = (size_t)BATCH * NTOT;
  float v1 = ((y[4 + lane] + y[P + 4 + lane]) + y[2 * P + 4 + lane]) + y[3 * P + 4 + lane];
  float best = v1;
  float sec  = -1e30f;
  int   cls  = lane;
  if (lane < 16) {
    float v2 = ((y[68 + lane] + y[P + 68 + lane]) + y[2 * P + 68 + lane]) + y[3 * P + 68 + lane];
    if (v2 > best) { sec = best; best = v2; cls = 64 + lane; }
    else           { sec = v2; }
  }
  #pragma unroll
  for (int off = 32; off > 0; off >>= 1) {
    float ob = __shfl_down(best, off);
    float os = __shfl_down(sec, off);
    int   oc = __shfl_down(cls, off);
    if (ob > best || (ob == best && oc < cls)) {
      sec = fmaxf(best, os); best = ob; cls = oc;
    } else {
      sec = fmaxf(ob, sec);
    }
  }
  if (lane == 0) {
    sc[task]   = (double)best;
    sc32[task] = best;
    cid[task]  = cls;
    flg[task]  = (best - sec < MARGIN_ARGMAX) ? 1 : 0;
  }
}

// ---------------- Kernel 3b: per-batch rank-tightness pair scan -------------
// Flags (bit1) every query whose fp32 score lies within PAIR_BASE of another
// query's (inflated near argmax-tight queries, whose score may move by up to
// MARGIN_ARGMAX after rescue). Flagged queries get fp64 rank scores.
__global__ __launch_bounds__(256) void pairscan_kernel(const float* __restrict__ sc32,
                                                       int* __restrict__ flg) {
  __shared__ float s[NQ];
  __shared__ int   f[NQ];
  int b = blockIdx.x;
  int t = threadIdx.x;
  for (int q = t; q < NQ; q += 256) {
    s[q] = sc32[b * NQ + q];
    f[q] = flg[b * NQ + q];
  }
  __syncthreads();
  for (int q = t; q < NQ; q += 256) {
    float sq = s[q];
    int   fq = f[q];
    int   hit = 0;
    for (int j = 0; j < NQ; ++j) {
      float thr = PAIR_BASE + (((fq | f[j]) & 1) ? PAIR_INFLATE : 0.0f);
      hit |= (j != q) & (fabsf(sq - s[j]) < thr);
    }
    if (hit) flg[b * NQ + q] = fq | 2;
  }
}

// ---------------- Kernel 3c: fp64 rescue for flagged queries ----------------
// One wave per (b,q); early-exit if unflagged (expected ~97% of waves).
// bit0: recompute all 80 class channels in fp64 (lane<->channel, coalesced W
//       reads), fp64 argmax with numpy tie rule -> sc, cid.
// bit1 only: fp64 dot of the (margin-safe) winning channel -> sc.
// fp64 values are ~1e-15 from the numpy fp64 reference; fp32/fp64 score order
// is consistent because unflagged gaps exceed PAIR_BASE >> fp32 error.
__global__ __launch_bounds__(256) void rescue_kernel(const double* __restrict__ At,
                                                     const float* __restrict__ W,
                                                     const int* __restrict__ flg,
                                                     double* __restrict__ sc,
                                                     int* __restrict__ cid) {
  int wave = threadIdx.x >> 6;
  int lane = threadIdx.x & 63;
  int task = blockIdx.x * 4 + wave;            // 0 .. 19199
  int f = flg[task];
  if (f == 0) return;
  int b = task / NQ;
  int q = task - b * NQ;
  if (f & 1) {
    // full fp64 argmax: lane -> class ch lane; lanes 0..15 also ch 64+lane
    const float* Wq = W + q * NCH + 4;
    double a1 = 0.0, a2 = 0.0;
    for (int k = 0; k < KDIM; ++k) {
      double a = At[k * 64 + b];               // wave-uniform scalar load
      a1 = fma(a, (double)Wq[(size_t)k * NTOT + lane], a1);
      if (lane < 16)
        a2 = fma(a, (double)Wq[(size_t)k * NTOT + 64 + lane], a2);
    }
    double best = a1;
    int    cls  = lane;
    if (lane < 16 && a2 > best) { best = a2; cls = 64 + lane; }  // strict >
    #pragma unroll
    for (int off = 32; off > 0; off >>= 1) {
      double ob = __shfl_down(best, off);
      int    oc = __shfl_down(cls, off);
      if (ob > best || (ob == best && oc < cls)) { best = ob; cls = oc; }
    }
    if (lane == 0) { sc[task] = best; cid[task] = cls; }
  } else {
    // rank-only: fp64 dot of winning channel, lanes split k, butterfly sum
    const float* Wc = W + q * NCH + 4 + cid[task];
    double s = 0.0;
    for (int t = 0; t < 19; ++t) {
      int k = lane + 64 * t;
      if (k < KDIM) s = fma(At[k * 64 + b], (double)Wc[(size_t)k * NTOT], s);
    }
    #pragma unroll
    for (int off = 32; off > 0; off >>= 1) s += __shfl_xor(s, off);
    if (lane == 0) sc[task] = s;
  }
}

// ---------------- Kernel 4: stable top-150 by rank selection ----------------
// One block per batch; fp64 scores in LDS; exact rank (score desc, q asc);
// only winners read boxes from Yf (fixed-order fp32 4-partial sums).
__global__ __launch_bounds__(256) void select_kernel(const float* __restrict__ Yf,
                                                     const double* __restrict__ sc,
                                                     const int* __restrict__ cid,
                                                     float* __restrict__ out) {
  __shared__ double ssc[NQ];
  __shared__ int    scid[NQ];
  int b = blockIdx.x;
  int t = threadIdx.x;
  for (int q = t; q < NQ; q += 256) {
    ssc[q]  = sc[b * NQ + q];
    scid[q] = cid[b * NQ + q];
  }
  __syncthreads();
  const size_t P = (size_t)BATCH * NTOT;
  for (int q = t; q < NQ; q += 256) {
    double s = ssc[q];
    int rank = 0;
    for (int j = 0; j < NQ; ++j) {
      double sj = ssc[j];
      rank += (sj > s) || (sj == s && j < q);
    }
    if (rank < KTOP) {
      const float* r0 = Yf + (size_t)b * NTOT + q * NCH;
      float* o = out + ((size_t)b * KTOP + rank) * 6;
      o[0] = ((r0[0] + r0[P + 0]) + r0[2 * P + 0]) + r0[3 * P + 0];
      o[1] = ((r0[1] + r0[P + 1]) + r0[2 * P + 1]) + r0[3 * P + 1];
      o[2] = ((r0[2] + r0[P + 2]) + r0[2 * P + 2]) + r0[3 * P + 2];
      o[3] = ((r0[3] + r0[P + 3]) + r0[2 * P + 3]) + r0[3 * P + 3];
      o[4] = (float)s;
      o[5] = (float)scid[q];
    }
  }
}

extern "C" void kernel_launch(void* const* d_in, const int* in_sizes, int n_in,
                              void* d_out, int out_size, void* d_ws, size_t ws_size,
                              hipStream_t stream) {
  const int*   x = (const int*)d_in[0];
  const float* W = (const float*)d_in[1];
  double* At   = (double*)d_ws;
  float*  Af   = (float*)((char*)d_ws + WS_AF);
  float*  Yf   = (float*)((char*)d_ws + WS_YF);
  double* sc   = (double*)((char*)d_ws + WS_SC);
  float*  sc32 = (float*)((char*)d_ws + WS_SC32);
  int*    cid  = (int*)((char*)d_ws + WS_CID);
  int*    flg  = (int*)((char*)d_ws + WS_FLG);
  pool_kernel<<<dim3(19200), dim3(256), 0, stream>>>(x, At, Af);
  gemm_kernel<<<dim3(197, NCHUNK), dim3(512), 0, stream>>>(Af, W, Yf);
  argmax_kernel<<<dim3(4800), dim3(256), 0, stream>>>(Yf, sc, sc32, cid, flg);
  pairscan_kernel<<<dim3(64), dim3(256), 0, stream>>>(sc32, flg);
  rescue_kernel<<<dim3(4800), dim3(256), 0, stream>>>(At, W, flg, sc, cid);
  select_kernel<<<dim3(64), dim3(256), 0, stream>>>(Yf, sc, cid, (float*)d_out);
}

// Round 7
// 667.515 us; speedup vs baseline: 1.3891x; 1.3891x over previous
//
#include <hip/hip_runtime.h>
#include <stdint.h>

#define BATCH 64
#define NQ 300
#define NCH 84            // 4 + 80
#define KTOP 150
#define NTOT (NQ * NCH)   // 25200
#define KDIM 1200
#define NCHUNK 4
#define KCH 300           // K per chunk (4 chunks)
#define HW 640
#define PF 6              // W prefetch depth (KCH % PF == 0)
#define RU 16             // rescue k-unroll (KDIM % RU == 0)

#define MARGIN_ARGMAX 1e-4f   // ~45x max statistical fp32 accum error (2.2e-6)
#define PAIR_BASE     2e-5f   // rank-tightness radius (9x max fp32 error)
#define PAIR_INFLATE  1.2e-4f // extra radius near argmax-tight queries

// ws layout (bytes), fp32 pipeline + fp64 rescue:
//   At  : [0, 614400)            1200*64 double   (for fp64 rescue)
//   Af  : [614400, 921600)       1200*64 float    (GEMM A operand)
//   Yf  : [921600, 26726400)     4 * 64*25200 float (K-chunk partials)
//   sc  : [26726400, 26880000)   64*300 double  (final ranking scores)
//   sc32: [26880000, 26956800)   64*300 float   (fp32 scores for pair scan)
//   cid : [26956800, 27033600)   64*300 int
//   flg : [27033600, 27110400)   64*300 int  (bit0: argmax-tight, bit1: rank-tight)
#define WS_AF   614400
#define WS_YF   921600
#define WS_SC   26726400
#define WS_SC32 26880000
#define WS_CID  26956800
#define WS_FLG  27033600

// ---------------- Kernel 1: 32x32 average pool (exact int sum) --------------
// x: (64,3,640,640) int32 -> At (fp64) and Af (fp32), both [k*64+b], where
// flat k = c_new*400 + ph*20 + pw, c_new = 2 - c_in (BGR flip).
// (float)s exact (s <= 261120 < 2^24); single rounding on the scale.
__global__ __launch_bounds__(256) void pool_kernel(const int* __restrict__ x,
                                                   double* __restrict__ At,
                                                   float* __restrict__ Af) {
  int wave = threadIdx.x >> 6;
  int lane = threadIdx.x & 63;
  int cell = blockIdx.x * 4 + wave;            // 0 .. 76799
  int b   = cell / 1200;
  int rem = cell - b * 1200;
  int cin = rem / 400;
  int pp  = rem - cin * 400;                   // ph*20 + pw
  int ph = pp / 20, pw = pp - ph * 20;
  const int* base = x + (((b * 3 + cin) * HW) + ph * 32) * HW + pw * 32;
  int r  = lane >> 1;                          // 0..31 (row in block)
  int c0 = (lane & 1) * 16;                    // 0 or 16 (col in block)
  const int4* p = (const int4*)(base + r * HW + c0);
  int4 v0 = p[0], v1 = p[1], v2 = p[2], v3 = p[3];
  int s = v0.x + v0.y + v0.z + v0.w + v1.x + v1.y + v1.z + v1.w
        + v2.x + v2.y + v2.z + v2.w + v3.x + v3.y + v3.z + v3.w;
  #pragma unroll
  for (int off = 32; off > 0; off >>= 1) s += __shfl_down(s, off);
  if (lane == 0) {
    int kout = (2 - cin) * 400 + pp;
    At[kout * 64 + b] = (double)s * (1.0 / 261120.0);   // / (255*1024)
    Af[kout * 64 + b] = (float)s * (1.0f / 261120.0f);
  }
}

// ---------------- Kernel 2: fp32 GEMM, W-read-once, 2 cols/lane -------------
// Af: (1200,64) float  W: (1200,25200) float  Yf: (4, 64, 25200) float
// blockIdx.y = K chunk. 512-thread block = 8 waves x 8 rows = all 64 rows
// (W read exactly once); each lane owns 2 adjacent output columns (float2 W
// load, float2 Y store), A as two float4 per k. Verified passing in R6.
__global__ __launch_bounds__(512) void gemm_kernel(const float* __restrict__ Af,
                                                   const float* __restrict__ W,
                                                   float* __restrict__ Yf) {
  int wave  = threadIdx.x >> 6;
  int lane  = threadIdx.x & 63;
  int chunk = blockIdx.y;
  int row0  = __builtin_amdgcn_readfirstlane((int)(wave * 8));
  int n  = blockIdx.x * 128 + 2 * lane;        // first of this lane's 2 cols
  int nl = n < NTOT - 1 ? n : NTOT - 2;        // clamp (even, no divergent load)
  const float4* Ap = (const float4*)(Af + (size_t)chunk * KCH * 64 + row0);
  const float*  Wp = W + (size_t)chunk * KCH * NTOT + nl;
  float acc0[8], acc1[8];
  #pragma unroll
  for (int i = 0; i < 8; ++i) { acc0[i] = 0.0f; acc1[i] = 0.0f; }
  float2 w[PF];
  #pragma unroll
  for (int u = 0; u < PF; ++u) w[u] = *(const float2*)(Wp + (size_t)u * NTOT);
  #pragma unroll 1
  for (int k0 = 0; k0 < KCH; k0 += PF) {
    int kn = (k0 + PF == KCH) ? 0 : k0 + PF;   // last prefetch wraps (unused)
    float2 wn[PF];
    #pragma unroll
    for (int u = 0; u < PF; ++u) wn[u] = *(const float2*)(Wp + (size_t)(kn + u) * NTOT);
    #pragma unroll
    for (int u = 0; u < PF; ++u) {
      float w0 = w[u].x, w1 = w[u].y;
      float4 a0 = Ap[(k0 + u) * 16 + 0];       // rows row0+0..3 at k=k0+u
      float4 a1 = Ap[(k0 + u) * 16 + 1];       // rows row0+4..7
      acc0[0] = fmaf(a0.x, w0, acc0[0]);  acc1[0] = fmaf(a0.x, w1, acc1[0]);
      acc0[1] = fmaf(a0.y, w0, acc0[1]);  acc1[1] = fmaf(a0.y, w1, acc1[1]);
      acc0[2] = fmaf(a0.z, w0, acc0[2]);  acc1[2] = fmaf(a0.z, w1, acc1[2]);
      acc0[3] = fmaf(a0.w, w0, acc0[3]);  acc1[3] = fmaf(a0.w, w1, acc1[3]);
      acc0[4] = fmaf(a1.x, w0, acc0[4]);  acc1[4] = fmaf(a1.x, w1, acc1[4]);
      acc0[5] = fmaf(a1.y, w0, acc0[5]);  acc1[5] = fmaf(a1.y, w1, acc1[5]);
      acc0[6] = fmaf(a1.z, w0, acc0[6]);  acc1[6] = fmaf(a1.z, w1, acc1[6]);
      acc0[7] = fmaf(a1.w, w0, acc0[7]);  acc1[7] = fmaf(a1.w, w1, acc1[7]);
    }
    #pragma unroll
    for (int u = 0; u < PF; ++u) w[u] = wn[u];
  }
  if (n < NTOT) {                              // n even -> n+1 also in range
    float* Yp = Yf + ((size_t)chunk * BATCH + row0) * NTOT + n;
    #pragma unroll
    for (int i = 0; i < 8; ++i) {
      float2 o; o.x = acc0[i]; o.y = acc1[i];
      *(float2*)(Yp + (size_t)i * NTOT) = o;
    }
  }
}

// ---------------- Kernel 3a: fp32 argmax + margin flag ----------------------
// One wave per (b,q). Fixed-order 4-partial sums; tracks best AND second-best.
// flags bit0 set when margin < MARGIN_ARGMAX (fp64 rescue needed).
__global__ __launch_bounds__(256) void argmax_kernel(const float* __restrict__ Yf,
                                                     double* __restrict__ sc,
                                                     float* __restrict__ sc32,
                                                     int* __restrict__ cid,
                                                     int* __restrict__ flg) {
  int wave = threadIdx.x >> 6;
  int lane = threadIdx.x & 63;
  int task = blockIdx.x * 4 + wave;            // 0 .. 19199
  int b = task / NQ;
  int q = task - b * NQ;
  const float* y = Yf + (size_t)b * NTOT + q * NCH;
  const size_t P = (size_t)BATCH * NTOT;
  float v1 = ((y[4 + lane] + y[P + 4 + lane]) + y[2 * P + 4 + lane]) + y[3 * P + 4 + lane];
  float best = v1;
  float sec  = -1e30f;
  int   cls  = lane;
  if (lane < 16) {
    float v2 = ((y[68 + lane] + y[P + 68 + lane]) + y[2 * P + 68 + lane]) + y[3 * P + 68 + lane];
    if (v2 > best) { sec = best; best = v2; cls = 64 + lane; }
    else           { sec = v2; }
  }
  #pragma unroll
  for (int off = 32; off > 0; off >>= 1) {
    float ob = __shfl_down(best, off);
    float os = __shfl_down(sec, off);
    int   oc = __shfl_down(cls, off);
    if (ob > best || (ob == best && oc < cls)) {
      sec = fmaxf(best, os); best = ob; cls = oc;
    } else {
      sec = fmaxf(ob, sec);
    }
  }
  if (lane == 0) {
    sc[task]   = (double)best;
    sc32[task] = best;
    cid[task]  = cls;
    flg[task]  = (best - sec < MARGIN_ARGMAX) ? 1 : 0;
  }
}

// ---------------- Kernel 3b: per-batch rank-tightness pair scan -------------
// Flags (bit1) every query whose fp32 score lies within PAIR_BASE of another
// query's (inflated near argmax-tight queries, whose score may move by up to
// MARGIN_ARGMAX after rescue). Flagged queries get fp64 rank scores.
__global__ __launch_bounds__(256) void pairscan_kernel(const float* __restrict__ sc32,
                                                       int* __restrict__ flg) {
  __shared__ float s[NQ];
  __shared__ int   f[NQ];
  int b = blockIdx.x;
  int t = threadIdx.x;
  for (int q = t; q < NQ; q += 256) {
    s[q] = sc32[b * NQ + q];
    f[q] = flg[b * NQ + q];
  }
  __syncthreads();
  for (int q = t; q < NQ; q += 256) {
    float sq = s[q];
    int   fq = f[q];
    int   hit = 0;
    for (int j = 0; j < NQ; ++j) {
      float thr = PAIR_BASE + (((fq | f[j]) & 1) ? PAIR_INFLATE : 0.0f);
      hit |= (j != q) & (fabsf(sq - s[j]) < thr);
    }
    if (hit) flg[b * NQ + q] = fq | 2;
  }
}

// ---------------- Kernel 3c: fp64 rescue for flagged queries ----------------
// One wave per (b,q); early-exit if unflagged (~97.5% of waves).
// R6 post-mortem: this kernel was 350 us because the k-loop was a SERIAL
// latency chain (1200 x ~600cyc un-overlapped L3/HBM round-trips, ~20 active
// waves). Fix: batch the latency — unroll k by RU=16 (16 scalar At loads +
// 32 coalesced W rows in flight per group), and fully unroll the 19-step
// rank-only path. Same arithmetic, same order, same results as R6 (passed).
__global__ __launch_bounds__(256) void rescue_kernel(const double* __restrict__ At,
                                                     const float* __restrict__ W,
                                                     const int* __restrict__ flg,
                                                     double* __restrict__ sc,
                                                     int* __restrict__ cid) {
  int wave = threadIdx.x >> 6;
  int lane = threadIdx.x & 63;
  int task = blockIdx.x * 4 + wave;            // 0 .. 19199
  int f = flg[task];
  if (f == 0) return;
  int b = task / NQ;
  int q = task - b * NQ;
  if (f & 1) {
    // full fp64 argmax: lane -> class ch lane; lanes 0..15 also ch 64+(lane&15).
    // ch2 loaded unconditionally (always in-bounds); a2 unused for lane>=16.
    const float* Wq = W + q * NCH + 4;
    int ch2 = 64 + (lane & 15);
    double a1 = 0.0, a2 = 0.0;
    #pragma unroll 1
    for (int k0 = 0; k0 < KDIM; k0 += RU) {
      double av[RU];
      float  w1v[RU], w2v[RU];
      #pragma unroll
      for (int u = 0; u < RU; ++u) {
        av[u]  = At[(k0 + u) * 64 + b];        // wave-uniform scalar loads
        w1v[u] = Wq[(size_t)(k0 + u) * NTOT + lane];
        w2v[u] = Wq[(size_t)(k0 + u) * NTOT + ch2];
      }
      #pragma unroll
      for (int u = 0; u < RU; ++u) {
        a1 = fma(av[u], (double)w1v[u], a1);
        a2 = fma(av[u], (double)w2v[u], a2);
      }
    }
    double best = a1;
    int    cls  = lane;
    if (lane < 16 && a2 > best) { best = a2; cls = 64 + lane; }  // strict >
    #pragma unroll
    for (int off = 32; off > 0; off >>= 1) {
      double ob = __shfl_down(best, off);
      int    oc = __shfl_down(cls, off);
      if (ob > best || (ob == best && oc < cls)) { best = ob; cls = oc; }
    }
    if (lane == 0) { sc[task] = best; cid[task] = cls; }
  } else {
    // rank-only: fp64 dot of winning channel, lanes split k, butterfly sum.
    // Fully unrolled: all 19 load pairs issued before the fma chain needs them.
    const float* Wc = W + q * NCH + 4 + cid[task];
    double av[19];
    float  wv[19];
    #pragma unroll
    for (int t = 0; t < 19; ++t) {
      int k = lane + 64 * t;
      int km = k < KDIM ? k : 0;               // clamp; masked out below
      av[t] = At[km * 64 + b];
      wv[t] = Wc[(size_t)km * NTOT];
    }
    double s = 0.0;
    #pragma unroll
    for (int t = 0; t < 19; ++t) {
      if (lane + 64 * t < KDIM) s = fma(av[t], (double)wv[t], s);
    }
    #pragma unroll
    for (int off = 32; off > 0; off >>= 1) s += __shfl_xor(s, off);
    if (lane == 0) sc[task] = s;
  }
}

// ---------------- Kernel 4: stable top-150 by rank selection ----------------
// One block per batch; fp64 scores in LDS; exact rank (score desc, q asc);
// only winners read boxes from Yf (fixed-order fp32 4-partial sums).
__global__ __launch_bounds__(256) void select_kernel(const float* __restrict__ Yf,
                                                     const double* __restrict__ sc,
                                                     const int* __restrict__ cid,
                                                     float* __restrict__ out) {
  __shared__ double ssc[NQ];
  __shared__ int    scid[NQ];
  int b = blockIdx.x;
  int t = threadIdx.x;
  for (int q = t; q < NQ; q += 256) {
    ssc[q]  = sc[b * NQ + q];
    scid[q] = cid[b * NQ + q];
  }
  __syncthreads();
  const size_t P = (size_t)BATCH * NTOT;
  for (int q = t; q < NQ; q += 256) {
    double s = ssc[q];
    int rank = 0;
    for (int j = 0; j < NQ; ++j) {
      double sj = ssc[j];
      rank += (sj > s) || (sj == s && j < q);
    }
    if (rank < KTOP) {
      const float* r0 = Yf + (size_t)b * NTOT + q * NCH;
      float* o = out + ((size_t)b * KTOP + rank) * 6;
      o[0] = ((r0[0] + r0[P + 0]) + r0[2 * P + 0]) + r0[3 * P + 0];
      o[1] = ((r0[1] + r0[P + 1]) + r0[2 * P + 1]) + r0[3 * P + 1];
      o[2] = ((r0[2] + r0[P + 2]) + r0[2 * P + 2]) + r0[3 * P + 2];
      o[3] = ((r0[3] + r0[P + 3]) + r0[2 * P + 3]) + r0[3 * P + 3];
      o[4] = (float)s;
      o[5] = (float)scid[q];
    }
  }
}

extern "C" void kernel_launch(void* const* d_in, const int* in_sizes, int n_in,
                              void* d_out, int out_size, void* d_ws, size_t ws_size,
                              hipStream_t stream) {
  const int*   x = (const int*)d_in[0];
  const float* W = (const float*)d_in[1];
  double* At   = (double*)d_ws;
  float*  Af   = (float*)((char*)d_ws + WS_AF);
  float*  Yf   = (float*)((char*)d_ws + WS_YF);
  double* sc   = (double*)((char*)d_ws + WS_SC);
  float*  sc32 = (float*)((char*)d_ws + WS_SC32);
  int*    cid  = (int*)((char*)d_ws + WS_CID);
  int*    flg  = (int*)((char*)d_ws + WS_FLG);
  pool_kernel<<<dim3(19200), dim3(256), 0, stream>>>(x, At, Af);
  gemm_kernel<<<dim3(197, NCHUNK), dim3(512), 0, stream>>>(Af, W, Yf);
  argmax_kernel<<<dim3(4800), dim3(256), 0, stream>>>(Yf, sc, sc32, cid, flg);
  pairscan_kernel<<<dim3(64), dim3(256), 0, stream>>>(sc32, flg);
  rescue_kernel<<<dim3(4800), dim3(256), 0, stream>>>(At, W, flg, sc, cid);
  select_kernel<<<dim3(64), dim3(256), 0, stream>>>(Yf, sc, cid, (float*)d_out);
}

// Round 8
// 621.809 us; speedup vs baseline: 1.4912x; 1.0735x over previous
//
#include <hip/hip_runtime.h>
#include <stdint.h>

#define BATCH 64
#define NQ 300
#define NCH 84            // 4 + 80
#define KTOP 150
#define NTOT (NQ * NCH)   // 25200
#define KDIM 1200
#define NCHUNK 4
#define KCH 300           // K per chunk (4 chunks)
#define HW 640
#define PF 6              // W prefetch depth (KCH % PF == 0)

// ws layout (bytes), fp64 pipeline, 4 K-chunk partials:
//   At : [0, 614400)                    1200*64 double
//   Y  : [614400, 52224000)             4 * 64*25200 double (K-chunk partials)
#define WS_Y   614400

// ---------------- Kernel 1: 32x32 average pool (exact int sum) --------------
// x: (64,3,640,640) int32  ->  At: (1200, 64) double   (A transposed)
// flat k = c_new*400 + ph*20 + pw, where c_new = 2 - c_in  (BGR flip)
__global__ __launch_bounds__(256) void pool_kernel(const int* __restrict__ x,
                                                   double* __restrict__ At) {
  int wave = threadIdx.x >> 6;
  int lane = threadIdx.x & 63;
  int cell = blockIdx.x * 4 + wave;            // 0 .. 76799
  int b   = cell / 1200;
  int rem = cell - b * 1200;
  int cin = rem / 400;
  int pp  = rem - cin * 400;                   // ph*20 + pw
  int ph = pp / 20, pw = pp - ph * 20;
  const int* base = x + (((b * 3 + cin) * HW) + ph * 32) * HW + pw * 32;
  int r  = lane >> 1;                          // 0..31 (row in block)
  int c0 = (lane & 1) * 16;                    // 0 or 16 (col in block)
  const int4* p = (const int4*)(base + r * HW + c0);
  int4 v0 = p[0], v1 = p[1], v2 = p[2], v3 = p[3];
  int s = v0.x + v0.y + v0.z + v0.w + v1.x + v1.y + v1.z + v1.w
        + v2.x + v2.y + v2.z + v2.w + v3.x + v3.y + v3.z + v3.w;
  #pragma unroll
  for (int off = 32; off > 0; off >>= 1) s += __shfl_down(s, off);
  if (lane == 0) {
    int kout = (2 - cin) * 400 + pp;
    At[kout * 64 + b] = (double)s * (1.0 / 261120.0);  // / (255*1024)
  }
}

// ---------------- Kernel 2: fp64 GEMM, issue-slot-minimized (R5, passing) ---
// At: (1200,64) double   W: (1200,25200) float   Y: (4, 64, 25200) double
// 512-thread block = 8 waves x 8 rows = all 64 batch rows (W read exactly
// once); each lane owns TWO adjacent output columns (float2 W load, double2
// Y store), A as double2. Per-output fma order (k ascending within chunk,
// fixed 4-partial order downstream) identical to R4/R5 passing kernels.
__global__ __launch_bounds__(512) void gemm_kernel(const double* __restrict__ At,
                                                   const float* __restrict__ W,
                                                   double* __restrict__ Y) {
  int wave  = threadIdx.x >> 6;
  int lane  = threadIdx.x & 63;
  int chunk = blockIdx.y;
  int row0  = __builtin_amdgcn_readfirstlane((int)(wave * 8));
  int n  = blockIdx.x * 128 + 2 * lane;        // first of this lane's 2 cols
  int nl = n < NTOT - 1 ? n : NTOT - 2;        // clamp (even, no divergent load)
  const double2* Ap = (const double2*)(At + (size_t)chunk * KCH * 64 + row0);
  const float*   Wp = W + (size_t)chunk * KCH * NTOT + nl;
  double acc0[8], acc1[8];
  #pragma unroll
  for (int i = 0; i < 8; ++i) { acc0[i] = 0.0; acc1[i] = 0.0; }
  float2 w[PF];
  #pragma unroll
  for (int u = 0; u < PF; ++u) w[u] = *(const float2*)(Wp + (size_t)u * NTOT);
  #pragma unroll 1
  for (int k0 = 0; k0 < KCH; k0 += PF) {
    int kn = (k0 + PF == KCH) ? 0 : k0 + PF;   // last prefetch wraps (unused)
    float2 wn[PF];
    #pragma unroll
    for (int u = 0; u < PF; ++u) wn[u] = *(const float2*)(Wp + (size_t)(kn + u) * NTOT);
    #pragma unroll
    for (int u = 0; u < PF; ++u) {
      double wd0 = (double)w[u].x;
      double wd1 = (double)w[u].y;
      #pragma unroll
      for (int j = 0; j < 4; ++j) {
        double2 a = Ap[(size_t)(k0 + u) * 32 + j]; // rows row0+2j, row0+2j+1
        acc0[2 * j]     = fma(a.x, wd0, acc0[2 * j]);
        acc1[2 * j]     = fma(a.x, wd1, acc1[2 * j]);
        acc0[2 * j + 1] = fma(a.y, wd0, acc0[2 * j + 1]);
        acc1[2 * j + 1] = fma(a.y, wd1, acc1[2 * j + 1]);
      }
    }
    #pragma unroll
    for (int u = 0; u < PF; ++u) w[u] = wn[u];
  }
  if (n < NTOT) {                              // n even; n+1 in range too
    double* Yp = Y + ((size_t)chunk * BATCH + row0) * NTOT + n;
    #pragma unroll
    for (int i = 0; i < 8; ++i) {
      double2 o; o.x = acc0[i]; o.y = acc1[i];
      *(double2*)(Yp + (size_t)i * NTOT) = o;
    }
  }
}

// ---------------- Kernel 3: fused argmax + stable top-150 select ------------
// One block per batch (512 threads = 8 waves).
// Phase 1 (argmax): waves stride queries; per query, R5's wave-argmax over 80
//   classes with fixed-order 4-partial sums (((c0+c1)+c2)+c3), tie -> smaller
//   class index. Result -> LDS (never round-trips global).
// Phase 2 (select): exact rank under (score desc, q asc); only the 150
//   winners read boxes from Y. Arithmetic bit-identical to R5's two kernels;
//   this fusion removes one dispatch + its inter-dispatch gap.
__global__ __launch_bounds__(512) void decide_kernel(const double* __restrict__ Y,
                                                     float* __restrict__ out) {
  __shared__ double ssc[NQ];
  __shared__ int    scid[NQ];
  int b    = blockIdx.x;
  int wave = threadIdx.x >> 6;                 // 0..7
  int lane = threadIdx.x & 63;
  const size_t P = (size_t)BATCH * NTOT;
  for (int q = wave; q < NQ; q += 8) {
    const double* y = Y + (size_t)b * NTOT + q * NCH;
    double best = ((y[4 + lane] + y[P + 4 + lane]) + y[2 * P + 4 + lane]) + y[3 * P + 4 + lane];
    int    cls  = lane;
    if (lane < 16) {
      double v2 = ((y[68 + lane] + y[P + 68 + lane]) + y[2 * P + 68 + lane]) + y[3 * P + 68 + lane];
      if (v2 > best) { best = v2; cls = 64 + lane; }   // strict > : lower idx wins ties
    }
    #pragma unroll
    for (int off = 32; off > 0; off >>= 1) {
      double ob = __shfl_down(best, off);
      int    oc = __shfl_down(cls, off);
      if (ob > best || (ob == best && oc < cls)) { best = ob; cls = oc; }
    }
    if (lane == 0) { ssc[q] = best; scid[q] = cls; }
  }
  __syncthreads();
  for (int q = threadIdx.x; q < NQ; q += 512) {
    double s = ssc[q];
    int rank = 0;
    for (int j = 0; j < NQ; ++j) {
      double sj = ssc[j];
      rank += (sj > s) || (sj == s && j < q);
    }
    if (rank < KTOP) {
      const double* r0 = Y + (size_t)b * NTOT + q * NCH;
      float* o = out + ((size_t)b * KTOP + rank) * 6;
      o[0] = (float)(((r0[0] + r0[P + 0]) + r0[2 * P + 0]) + r0[3 * P + 0]);
      o[1] = (float)(((r0[1] + r0[P + 1]) + r0[2 * P + 1]) + r0[3 * P + 1]);
      o[2] = (float)(((r0[2] + r0[P + 2]) + r0[2 * P + 2]) + r0[3 * P + 2]);
      o[3] = (float)(((r0[3] + r0[P + 3]) + r0[2 * P + 3]) + r0[3 * P + 3]);
      o[4] = (float)s;
      o[5] = (float)scid[q];
    }
  }
}

extern "C" void kernel_launch(void* const* d_in, const int* in_sizes, int n_in,
                              void* d_out, int out_size, void* d_ws, size_t ws_size,
                              hipStream_t stream) {
  const int*   x = (const int*)d_in[0];
  const float* W = (const float*)d_in[1];
  double* At  = (double*)d_ws;
  double* Y   = (double*)((char*)d_ws + WS_Y);
  pool_kernel<<<dim3(19200), dim3(256), 0, stream>>>(x, At);
  gemm_kernel<<<dim3(197, NCHUNK), dim3(512), 0, stream>>>(At, W, Y);
  decide_kernel<<<dim3(64), dim3(512), 0, stream>>>(Y, (float*)d_out);
}